// Round 3
// baseline (148.316 us; speedup 1.0000x reference)
//
#include <hip/hip_runtime.h>
#include <hip/hip_bf16.h>
#include <cstdint>
#include <cstddef>

#define B_N   32
#define CIN_  128
#define COUT_ 128
#define KW_   7
#define L_    4096
#define PAD_  3
#define NW_   256      // w-positions per block tile
#define BC_   32       // channels per K-chunk
#define RPB   4104     // exT rows per batch: r = l + 3, guards r<3 and r>4098
#define NWELEM (KW_ * COUT_ * CIN_)   // 114688
#define NGUARD (B_N * 8 * CIN_)       // 32768

#define SW_ELEMS (KW_ * COUT_ * BC_)  // 28672 bf16 = 57344 B per buffer
#define SX_ROWS  264                  // 262 used (256 w + 6 taps); pad to 264
#define SX_ELEMS (SX_ROWS * BC_)      // 8448 bf16 = 16896 B per buffer

typedef __attribute__((ext_vector_type(8))) short  bf16x8;
typedef __attribute__((ext_vector_type(4))) float  f32x4;

__device__ __forceinline__ void gl2lds16(const void* g, void* l) {
    __builtin_amdgcn_global_load_lds(
        (const __attribute__((address_space(1))) unsigned int*)g,
        (__attribute__((address_space(3))) unsigned int*)l, 16, 0, 0);
}

// exp+transpose of x (blocks x<64), plus weight-exp and exT guard-row zeroing
// (blocks x>=64, y==0) folded in to save a kernel launch.
__global__ __launch_bounds__(256) void exp_x_kernel(
        const float* __restrict__ x, __hip_bfloat16* __restrict__ exT,
        const float* __restrict__ w, __hip_bfloat16* __restrict__ ewb) {
    if (blockIdx.x >= 64) {
        if (blockIdx.y != 0) return;
        int base = (blockIdx.x - 64) * 256 + threadIdx.x;   // 18 blocks * 256 = 4608
        #pragma unroll
        for (int i = 0; i < 32; ++i) {
            int idx = base + 4608 * i;                      // covers 147456 = NWELEM+NGUARD
            if (idx < NWELEM) {
                int c = idx & 127, rest = idx >> 7;
                int o = rest & 127, k = rest >> 7;
                ewb[idx] = __float2bfloat16(__expf(w[(o * CIN_ + c) * KW_ + k]));
            } else {
                int j  = idx - NWELEM;
                int b  = j >> 10, rr = (j >> 7) & 7, c = j & 127;
                int r  = (rr < 3) ? rr : (4096 + rr);       // rows 0,1,2 and 4099..4103
                exT[((size_t)b * RPB + r) * CIN_ + c] = __float2bfloat16(0.0f);
            }
        }
        return;
    }

    __shared__ __align__(16) __hip_bfloat16 tileT[64 * 136];   // 17408 B
    const int b  = blockIdx.y;
    const int l0 = blockIdx.x * 64;
    const int tid = threadIdx.x;
    const float* xb = x + (size_t)b * CIN_ * L_ + l0;

    #pragma unroll
    for (int i = 0; i < 8; ++i) {
        int idx = tid + 256 * i;
        int c   = idx >> 4;               // 0..127
        int lv4 = (idx & 15) * 4;         // l offset 0..60
        f32x4 v = *(const f32x4*)(xb + (size_t)c * L_ + lv4);
        #pragma unroll
        for (int k2 = 0; k2 < 4; ++k2) {
            int l  = lv4 + k2;
            int sw = (l >> 2) & 15;
            tileT[l * 136 + (c ^ (sw << 3))] = __float2bfloat16(__expf(v[k2]));
        }
    }
    __syncthreads();

    __hip_bfloat16* dst = exT + ((size_t)b * RPB + l0 + PAD_) * CIN_;
    #pragma unroll
    for (int i = 0; i < 4; ++i) {
        int idx = tid + 256 * i;
        int l  = idx >> 4;                // 16 lanes per row -> 256 B coalesced
        int gc = idx & 15;                // channel granule (8 ch)
        int sw = (l >> 2) & 15;
        bf16x8 vv = *(const bf16x8*)&tileT[l * 136 + ((gc ^ sw) << 3)];
        *(bf16x8*)(dst + (size_t)l * CIN_ + gc * 8) = vv;
    }
}

// Conv GEMM, 2-phase double-buffered pipeline (T3 minimum recipe):
//   STAGE(chunk0) -> sync -> [STAGE(c+1); COMPUTE(c)] -> sync -> ... -> COMPUTE(3)
// Stage loads are ISSUED before the ~4300-cyc MFMA phase, so the vmcnt(0)
// inside the chunk-end __syncthreads() drains already-landed loads. Four
// distinct __shared__ arrays + fully-unrolled chunk loop keep buffer indices
// static so the compiler can disambiguate in-flight gl2lds writes (sW1/sX1)
// from concurrent ds_reads (sW0/sX0) and not serialize them.
// Block = 128 o x 256 w, 8 waves (2x4), wave tile 4x4 frags (64 acc VGPRs),
// 0.5 ds_read_b128 per MFMA. sW fragment-order (lane-linear, conflict-free);
// sX granule-slot XOR swizzle (<=2-way). LDS 148.5 KB -> 1 block/CU.
__global__ __launch_bounds__(512, 1) void tropconv_kernel(
        const __hip_bfloat16* __restrict__ exT,
        const __hip_bfloat16* __restrict__ ewb,
        const float* __restrict__ bias,
        float* __restrict__ out) {
    __shared__ __align__(16) __hip_bfloat16 sW0[SW_ELEMS];
    __shared__ __align__(16) __hip_bfloat16 sW1[SW_ELEMS];
    __shared__ __align__(16) __hip_bfloat16 sX0[SX_ELEMS];
    __shared__ __align__(16) __hip_bfloat16 sX1[SX_ELEMS];

    const int tid  = threadIdx.x;
    const int lane = tid & 63;
    const int wave = tid >> 6;
    const int wm   = wave >> 2;            // 0..1: o half (64 each)
    const int wn   = wave & 3;             // 0..3: w quarter (64 each)
    const int l15  = lane & 15;
    const int q    = lane >> 4;

    const int b  = blockIdx.y;
    const int w0 = blockIdx.x * NW_;
    const __hip_bfloat16* exb = exT + ((size_t)b * RPB + w0) * CIN_;

    // --- per-thread stage source offsets (element units); chunk adds c*32.
    // sW granule g = tid + 512*s: frag block blk=g>>6 = t*8+og, lane li=g&63
    // holds W[og*16 + (li&15)][(li>>4)*8 ..+8] at tap t.
    int woff[7];
    #pragma unroll
    for (int s = 0; s < 7; ++s) {
        int g  = tid + 512 * s;
        int li = g & 63, blk = g >> 6;
        int t  = blk >> 3, og = blk & 7;
        woff[s] = (((t << 7) + (og << 4) + (li & 15)) << 7) + ((li >> 4) << 3);
    }
    // sX granule gx: row p=gx>>2, slot j=gx&3 holds ch-granule j^((p>>1)&3).
    int xoff[2];
    #pragma unroll
    for (int s = 0; s < 2; ++s) {
        int gx = tid + 512 * s;
        int p = gx >> 2, j = gx & 3;
        xoff[s] = (p << 7) + (((j ^ ((p >> 1) & 3))) << 3);
    }
    const int gx2 = tid + 1024;            // partial round: rows 256..263
    const int p2  = gx2 >> 2;
    const int xoff2 = (p2 << 7) + ((((gx2 & 3) ^ ((p2 >> 1) & 3))) << 3);

#define STAGE(SWB, SXB, C0)                                                  \
    do {                                                                     \
        _Pragma("unroll")                                                    \
        for (int s = 0; s < 7; ++s)                                          \
            gl2lds16(ewb + woff[s] + (C0), &SWB[(tid + 512 * s) * 8]);       \
        _Pragma("unroll")                                                    \
        for (int s = 0; s < 2; ++s)                                          \
            gl2lds16(exb + xoff[s] + (C0), &SXB[(tid + 512 * s) * 8]);       \
        if (tid < 32)                                                        \
            gl2lds16(exb + xoff2 + (C0), &SXB[(tid + 1024) * 8]);            \
    } while (0)

#define COMPUTE(SWB, SXB)                                                    \
    do {                                                                     \
        _Pragma("unroll")                                                    \
        for (int t = 0; t < KW_; ++t) {                                      \
            bf16x8 af[4], bx[4];                                             \
            _Pragma("unroll")                                                \
            for (int mi = 0; mi < 4; ++mi) {                                 \
                int blk = t * 8 + wm * 4 + mi;                               \
                af[mi] = *(const bf16x8*)&SWB[((blk << 6) + lane) * 8];      \
            }                                                                \
            _Pragma("unroll")                                                \
            for (int ni = 0; ni < 4; ++ni) {                                 \
                int p = wn * 64 + ni * 16 + l15 + t;                         \
                bx[ni] = *(const bf16x8*)&SXB[(p << 5) +                     \
                                              ((q ^ ((p >> 1) & 3)) << 3)];  \
            }                                                                \
            __builtin_amdgcn_s_setprio(1);                                   \
            _Pragma("unroll")                                                \
            for (int mi = 0; mi < 4; ++mi)                                   \
                _Pragma("unroll")                                            \
                for (int ni = 0; ni < 4; ++ni)                               \
                    acc[mi][ni] = __builtin_amdgcn_mfma_f32_16x16x32_bf16(   \
                        af[mi], bx[ni], acc[mi][ni], 0, 0, 0);               \
            __builtin_amdgcn_s_setprio(0);                                   \
        }                                                                    \
    } while (0)

    f32x4 acc[4][4];
    #pragma unroll
    for (int i = 0; i < 4; ++i)
        #pragma unroll
        for (int j = 0; j < 4; ++j)
            acc[i][j] = (f32x4){0.f, 0.f, 0.f, 0.f};

    STAGE(sW0, sX0, 0);
    __syncthreads();                 // chunk 0 resident

    STAGE(sW1, sX1, 32);             // prefetch chunk 1 (in flight under MFMAs)
    COMPUTE(sW0, sX0);
    __syncthreads();                 // drains chunk-1 loads; readers of buf0 done

    STAGE(sW0, sX0, 64);             // prefetch chunk 2
    COMPUTE(sW1, sX1);
    __syncthreads();

    STAGE(sW1, sX1, 96);             // prefetch chunk 3
    COMPUTE(sW0, sX0);
    __syncthreads();

    COMPUTE(sW1, sX1);               // last chunk, nothing to prefetch

#undef STAGE
#undef COMPUTE

    // epilogue: y = log(s) + bias[o]; C/D: col=lane&15 (w), row=q*4+reg (cout)
    float* outb = out + (size_t)b * COUT_ * L_;
    #pragma unroll
    for (int mi = 0; mi < 4; ++mi) {
        #pragma unroll
        for (int r = 0; r < 4; ++r) {
            int o = wm * 64 + mi * 16 + q * 4 + r;
            float bv = bias[o];
            #pragma unroll
            for (int ni = 0; ni < 4; ++ni) {
                int w = w0 + wn * 64 + ni * 16 + l15;
                outb[(size_t)o * L_ + w] = __logf(acc[mi][ni][r]) + bv;
            }
        }
    }
}

extern "C" void kernel_launch(void* const* d_in, const int* in_sizes, int n_in,
                              void* d_out, int out_size, void* d_ws, size_t ws_size,
                              hipStream_t stream) {
    const float* x    = (const float*)d_in[0];   // (32,128,4096) f32
    const float* wgt  = (const float*)d_in[1];   // (128,128,7)   f32
    const float* bias = (const float*)d_in[2];   // (128,)        f32
    float* out = (float*)d_out;                  // (32,128,4096) f32

    // workspace: exT (32 x 4104 x 128 bf16 = 33,619,968 B), then ewb (229 KB)
    __hip_bfloat16* exT = (__hip_bfloat16*)d_ws;
    __hip_bfloat16* ewb = (__hip_bfloat16*)((char*)d_ws + (size_t)B_N * RPB * CIN_ * 2);

    exp_x_kernel<<<dim3(64 + 18, B_N), 256, 0, stream>>>(x, exT, wgt, ewb);
    tropconv_kernel<<<dim3(L_ / NW_, B_N), 512, 0, stream>>>(exT, ewb, bias, out);
}

// Round 4
// 147.040 us; speedup vs baseline: 1.0087x; 1.0087x over previous
//
#include <hip/hip_runtime.h>
#include <hip/hip_bf16.h>
#include <cstdint>
#include <cstddef>

#define B_N   32
#define CIN_  128
#define COUT_ 128
#define KW_   7
#define L_    4096
#define PAD_  3
#define NW_   256      // w-positions per block tile
#define BC_   32       // channels per K-chunk
#define RPB   4104     // exT rows per batch: r = l + 3, guards r<3 and r>4098
#define NWELEM (KW_ * COUT_ * CIN_)   // 114688
#define NGUARD (B_N * 8 * CIN_)       // 32768

#define SW_ELEMS (KW_ * COUT_ * BC_)  // 28672 bf16 = 57344 B per buffer
#define SX_ROWS  264                  // 262 used (256 w + 6 taps); pad to 264
#define SX_ELEMS (SX_ROWS * BC_)      // 8448 bf16 = 16896 B per buffer

typedef __attribute__((ext_vector_type(8))) short  bf16x8;
typedef __attribute__((ext_vector_type(4))) float  f32x4;

__device__ __forceinline__ void gl2lds16(const void* g, void* l) {
    __builtin_amdgcn_global_load_lds(
        (const __attribute__((address_space(1))) unsigned int*)g,
        (__attribute__((address_space(3))) unsigned int*)l, 16, 0, 0);
}

// exp+transpose of x (blocks x<64), plus weight-exp and exT guard-row zeroing
// (blocks x>=64, y==0) folded in to save a kernel launch.
__global__ __launch_bounds__(256) void exp_x_kernel(
        const float* __restrict__ x, __hip_bfloat16* __restrict__ exT,
        const float* __restrict__ w, __hip_bfloat16* __restrict__ ewb) {
    if (blockIdx.x >= 64) {
        if (blockIdx.y != 0) return;
        int base = (blockIdx.x - 64) * 256 + threadIdx.x;   // 18 blocks * 256 = 4608
        #pragma unroll
        for (int i = 0; i < 32; ++i) {
            int idx = base + 4608 * i;                      // covers 147456 = NWELEM+NGUARD
            if (idx < NWELEM) {
                int c = idx & 127, rest = idx >> 7;
                int o = rest & 127, k = rest >> 7;
                ewb[idx] = __float2bfloat16(__expf(w[(o * CIN_ + c) * KW_ + k]));
            } else {
                int j  = idx - NWELEM;
                int b  = j >> 10, rr = (j >> 7) & 7, c = j & 127;
                int r  = (rr < 3) ? rr : (4096 + rr);       // rows 0,1,2 and 4099..4103
                exT[((size_t)b * RPB + r) * CIN_ + c] = __float2bfloat16(0.0f);
            }
        }
        return;
    }

    __shared__ __align__(16) __hip_bfloat16 tileT[64 * 136];   // 17408 B
    const int b  = blockIdx.y;
    const int l0 = blockIdx.x * 64;
    const int tid = threadIdx.x;
    const float* xb = x + (size_t)b * CIN_ * L_ + l0;

    #pragma unroll
    for (int i = 0; i < 8; ++i) {
        int idx = tid + 256 * i;
        int c   = idx >> 4;               // 0..127
        int lv4 = (idx & 15) * 4;         // l offset 0..60
        f32x4 v = *(const f32x4*)(xb + (size_t)c * L_ + lv4);
        #pragma unroll
        for (int k2 = 0; k2 < 4; ++k2) {
            int l  = lv4 + k2;
            int sw = (l >> 2) & 15;
            tileT[l * 136 + (c ^ (sw << 3))] = __float2bfloat16(__expf(v[k2]));
        }
    }
    __syncthreads();

    __hip_bfloat16* dst = exT + ((size_t)b * RPB + l0 + PAD_) * CIN_;
    #pragma unroll
    for (int i = 0; i < 4; ++i) {
        int idx = tid + 256 * i;
        int l  = idx >> 4;                // 16 lanes per row -> 256 B coalesced
        int gc = idx & 15;                // channel granule (8 ch)
        int sw = (l >> 2) & 15;
        bf16x8 vv = *(const bf16x8*)&tileT[l * 136 + ((gc ^ sw) << 3)];
        *(bf16x8*)(dst + (size_t)l * CIN_ + gc * 8) = vv;
    }
}

// Conv GEMM, double-buffered chunks + register-pipelined tap loop.
// Round-3 lesson: stage overlap was already implicit; the real cost is a
// per-tap convoy: reads(t+1) could not issue until the tap-t MFMA burst
// drained the matrix pipe's issue slots -> LDS and MFMA pipes alternate
// instead of overlapping (34.8k + 43k cyc/CU serial ~= measured 104k).
// Fix: LOADT(t+1) issued BEFORE MFMA(t) into alternate register set
// (static names, rule #20), sched_barrier(0) pins the order. Compiler then
// emits counted lgkmcnt(8): each MFMA cluster waits only on reads that are
// one full cluster (~600 cyc) old. LDS floor 43k cyc/CU = 18 us.
__global__ __launch_bounds__(512, 1) void tropconv_kernel(
        const __hip_bfloat16* __restrict__ exT,
        const __hip_bfloat16* __restrict__ ewb,
        const float* __restrict__ bias,
        float* __restrict__ out) {
    __shared__ __align__(16) __hip_bfloat16 sW0[SW_ELEMS];
    __shared__ __align__(16) __hip_bfloat16 sW1[SW_ELEMS];
    __shared__ __align__(16) __hip_bfloat16 sX0[SX_ELEMS];
    __shared__ __align__(16) __hip_bfloat16 sX1[SX_ELEMS];

    const int tid  = threadIdx.x;
    const int lane = tid & 63;
    const int wave = tid >> 6;
    const int wm   = wave >> 2;            // 0..1: o half (64 each)
    const int wn   = wave & 3;             // 0..3: w quarter (64 each)
    const int l15  = lane & 15;
    const int q    = lane >> 4;

    const int b  = blockIdx.y;
    const int w0 = blockIdx.x * NW_;
    const __hip_bfloat16* exb = exT + ((size_t)b * RPB + w0) * CIN_;

    // --- per-thread stage source offsets (element units); chunk adds c*32.
    // sW granule g = tid + 512*s: frag block blk=g>>6 = t*8+og, lane li=g&63
    // holds W[og*16 + (li&15)][(li>>4)*8 ..+8] at tap t.
    int woff[7];
    #pragma unroll
    for (int s = 0; s < 7; ++s) {
        int g  = tid + 512 * s;
        int li = g & 63, blk = g >> 6;
        int t  = blk >> 3, og = blk & 7;
        woff[s] = (((t << 7) + (og << 4) + (li & 15)) << 7) + ((li >> 4) << 3);
    }
    // sX granule gx: row p=gx>>2, slot j=gx&3 holds ch-granule j^((p>>1)&3).
    int xoff[2];
    #pragma unroll
    for (int s = 0; s < 2; ++s) {
        int gx = tid + 512 * s;
        int p = gx >> 2, j = gx & 3;
        xoff[s] = (p << 7) + (((j ^ ((p >> 1) & 3))) << 3);
    }
    const int gx2 = tid + 1024;            // partial round: rows 256..263
    const int p2  = gx2 >> 2;
    const int xoff2 = (p2 << 7) + ((((gx2 & 3) ^ ((p2 >> 1) & 3))) << 3);

#define STAGE(SWB, SXB, C0)                                                  \
    do {                                                                     \
        _Pragma("unroll")                                                    \
        for (int s = 0; s < 7; ++s)                                          \
            gl2lds16(ewb + woff[s] + (C0), &SWB[(tid + 512 * s) * 8]);       \
        _Pragma("unroll")                                                    \
        for (int s = 0; s < 2; ++s)                                          \
            gl2lds16(exb + xoff[s] + (C0), &SXB[(tid + 512 * s) * 8]);       \
        if (tid < 32)                                                        \
            gl2lds16(exb + xoff2 + (C0), &SXB[(tid + 1024) * 8]);            \
    } while (0)

    // read tap T's fragments into named register set (AF, BX)
#define LOADT(SWB, SXB, T, AF, BX)                                           \
    do {                                                                     \
        _Pragma("unroll")                                                    \
        for (int mi = 0; mi < 4; ++mi)                                       \
            AF[mi] = *(const bf16x8*)&SWB[(((T) * 8 + wm * 4 + mi) << 6      \
                                           + 9 - 9 << 0) * 1                 \
                                          + ((((T) * 8 + wm * 4 + mi) << 6)  \
                                             + lane) * 8 * 0];               \
    } while (0)
#undef LOADT
#define LOADT(SWB, SXB, T, AF, BX)                                           \
    do {                                                                     \
        _Pragma("unroll")                                                    \
        for (int mi = 0; mi < 4; ++mi)                                       \
            AF[mi] = *(const bf16x8*)&SWB[((((T) * 8 + wm * 4 + mi) << 6)    \
                                           + lane) * 8];                     \
        _Pragma("unroll")                                                    \
        for (int ni = 0; ni < 4; ++ni) {                                     \
            int p = wn * 64 + ni * 16 + l15 + (T);                           \
            BX[ni] = *(const bf16x8*)&SXB[(p << 5) +                         \
                                          ((q ^ ((p >> 1) & 3)) << 3)];      \
        }                                                                    \
    } while (0)

    // MFMA cluster on a named register set; sched_barrier(0) fences keep the
    // preceding LOADT's ds_reads ABOVE the cluster (compiler may not sink
    // them past), so reads for t+1 are in flight while tap t crunches.
#define MFMAT(AF, BX)                                                        \
    do {                                                                     \
        __builtin_amdgcn_sched_barrier(0);                                   \
        __builtin_amdgcn_s_setprio(1);                                       \
        _Pragma("unroll")                                                    \
        for (int mi = 0; mi < 4; ++mi)                                       \
            _Pragma("unroll")                                                \
            for (int ni = 0; ni < 4; ++ni)                                   \
                acc[mi][ni] = __builtin_amdgcn_mfma_f32_16x16x32_bf16(       \
                    AF[mi], BX[ni], acc[mi][ni], 0, 0, 0);                   \
        __builtin_amdgcn_s_setprio(0);                                       \
        __builtin_amdgcn_sched_barrier(0);                                   \
    } while (0)

    // 7 taps, register double-buffered (sets A/B alternate; static indexing)
#define COMPUTE(SWB, SXB)                                                    \
    do {                                                                     \
        bf16x8 afA[4], bxA[4], afB[4], bxB[4];                               \
        LOADT(SWB, SXB, 0, afA, bxA);                                        \
        LOADT(SWB, SXB, 1, afB, bxB);  MFMAT(afA, bxA);   /* t0 */           \
        LOADT(SWB, SXB, 2, afA, bxA);  MFMAT(afB, bxB);   /* t1 */           \
        LOADT(SWB, SXB, 3, afB, bxB);  MFMAT(afA, bxA);   /* t2 */           \
        LOADT(SWB, SXB, 4, afA, bxA);  MFMAT(afB, bxB);   /* t3 */           \
        LOADT(SWB, SXB, 5, afB, bxB);  MFMAT(afA, bxA);   /* t4 */           \
        LOADT(SWB, SXB, 6, afA, bxA);  MFMAT(afB, bxB);   /* t5 */           \
        MFMAT(afA, bxA);                                  /* t6 */           \
    } while (0)

    f32x4 acc[4][4];
    #pragma unroll
    for (int i = 0; i < 4; ++i)
        #pragma unroll
        for (int j = 0; j < 4; ++j)
            acc[i][j] = (f32x4){0.f, 0.f, 0.f, 0.f};

    STAGE(sW0, sX0, 0);
    __syncthreads();                 // chunk 0 resident

    STAGE(sW1, sX1, 32);             // prefetch chunk 1 (in flight under MFMAs)
    COMPUTE(sW0, sX0);
    __syncthreads();                 // drains chunk-1 loads; readers of buf0 done

    STAGE(sW0, sX0, 64);             // prefetch chunk 2
    COMPUTE(sW1, sX1);
    __syncthreads();

    STAGE(sW1, sX1, 96);             // prefetch chunk 3
    COMPUTE(sW0, sX0);
    __syncthreads();

    COMPUTE(sW1, sX1);               // last chunk, nothing to prefetch

#undef STAGE
#undef LOADT
#undef MFMAT
#undef COMPUTE

    // epilogue: y = log(s) + bias[o]; C/D: col=lane&15 (w), row=q*4+reg (cout)
    float* outb = out + (size_t)b * COUT_ * L_;
    #pragma unroll
    for (int mi = 0; mi < 4; ++mi) {
        #pragma unroll
        for (int r = 0; r < 4; ++r) {
            int o = wm * 64 + mi * 16 + q * 4 + r;
            float bv = bias[o];
            #pragma unroll
            for (int ni = 0; ni < 4; ++ni) {
                int w = w0 + wn * 64 + ni * 16 + l15;
                outb[(size_t)o * L_ + w] = __logf(acc[mi][ni][r]) + bv;
            }
        }
    }
}

extern "C" void kernel_launch(void* const* d_in, const int* in_sizes, int n_in,
                              void* d_out, int out_size, void* d_ws, size_t ws_size,
                              hipStream_t stream) {
    const float* x    = (const float*)d_in[0];   // (32,128,4096) f32
    const float* wgt  = (const float*)d_in[1];   // (128,128,7)   f32
    const float* bias = (const float*)d_in[2];   // (128,)        f32
    float* out = (float*)d_out;                  // (32,128,4096) f32

    // workspace: exT (32 x 4104 x 128 bf16 = 33,619,968 B), then ewb (229 KB)
    __hip_bfloat16* exT = (__hip_bfloat16*)d_ws;
    __hip_bfloat16* ewb = (__hip_bfloat16*)((char*)d_ws + (size_t)B_N * RPB * CIN_ * 2);

    exp_x_kernel<<<dim3(64 + 18, B_N), 256, 0, stream>>>(x, exT, wgt, ewb);
    tropconv_kernel<<<dim3(L_ / NW_, B_N), 512, 0, stream>>>(exT, ewb, bias, out);
}

// Round 5
// 143.875 us; speedup vs baseline: 1.0309x; 1.0220x over previous
//
#include <hip/hip_runtime.h>
#include <hip/hip_bf16.h>
#include <cstdint>
#include <cstddef>

#define B_N   32
#define CIN_  128
#define COUT_ 128
#define KW_   7
#define L_    4096
#define PAD_  3
#define NW_   256      // w-positions per block tile
#define RPB   4104     // exT rows per batch: r = l + 3, guards r<3 and r>4098
#define NWELEM (KW_ * COUT_ * CIN_)   // 114688
#define NGUARD (B_N * 8 * CIN_)       // 32768

#define SX_ROWS  264                  // 262 used (256 w + 6 taps); pad to 264
#define SX_ELEMS (SX_ROWS * CIN_)     // 33792 bf16 = 67584 B

typedef __attribute__((ext_vector_type(8))) short  bf16x8;
typedef __attribute__((ext_vector_type(4))) float  f32x4;

__device__ __forceinline__ void gl2lds16(const void* g, void* l) {
    __builtin_amdgcn_global_load_lds(
        (const __attribute__((address_space(1))) unsigned int*)g,
        (__attribute__((address_space(3))) unsigned int*)l, 16, 0, 0);
}

// exp+transpose of x (blocks x<64), plus weight-exp (written directly in MFMA
// fragment order) and exT guard-row zeroing (blocks x>=64, y==0).
// ewb fragment layout: idx = (((t*8+og)*4+cc)*64 + li)*8 + e holds
// exp(W[og*16+(li&15)][cc*32+(li>>4)*8+e]) at tap t -- so tropconv loads a
// whole A-fragment as one coalesced 1KB wave read straight into VGPRs.
__global__ __launch_bounds__(256) void exp_x_kernel(
        const float* __restrict__ x, __hip_bfloat16* __restrict__ exT,
        const float* __restrict__ w, __hip_bfloat16* __restrict__ ewb) {
    if (blockIdx.x >= 64) {
        if (blockIdx.y != 0) return;
        int base = (blockIdx.x - 64) * 256 + threadIdx.x;   // 18 blocks * 256 = 4608
        #pragma unroll
        for (int i = 0; i < 32; ++i) {
            int idx = base + 4608 * i;                      // covers 147456 = NWELEM+NGUARD
            if (idx < NWELEM) {
                int e  = idx & 7;
                int li = (idx >> 3) & 63;
                int cc = (idx >> 9) & 3;
                int blk = idx >> 11;                        // 0..55
                int og = blk & 7, t = blk >> 3;
                int o  = og * 16 + (li & 15);
                int ch = cc * 32 + ((li >> 4) << 3) + e;
                ewb[idx] = __float2bfloat16(__expf(w[(o * CIN_ + ch) * KW_ + t]));
            } else {
                int j  = idx - NWELEM;
                int b  = j >> 10, rr = (j >> 7) & 7, c = j & 127;
                int r  = (rr < 3) ? rr : (4096 + rr);       // rows 0,1,2 and 4099..4103
                exT[((size_t)b * RPB + r) * CIN_ + c] = __float2bfloat16(0.0f);
            }
        }
        return;
    }

    __shared__ __align__(16) __hip_bfloat16 tileT[64 * 136];   // 17408 B
    const int b  = blockIdx.y;
    const int l0 = blockIdx.x * 64;
    const int tid = threadIdx.x;
    const float* xb = x + (size_t)b * CIN_ * L_ + l0;

    #pragma unroll
    for (int i = 0; i < 8; ++i) {
        int idx = tid + 256 * i;
        int c   = idx >> 4;               // 0..127
        int lv4 = (idx & 15) * 4;         // l offset 0..60
        f32x4 v = *(const f32x4*)(xb + (size_t)c * L_ + lv4);
        #pragma unroll
        for (int k2 = 0; k2 < 4; ++k2) {
            int l  = lv4 + k2;
            int sw = (l >> 2) & 15;
            tileT[l * 136 + (c ^ (sw << 3))] = __float2bfloat16(__expf(v[k2]));
        }
    }
    __syncthreads();

    __hip_bfloat16* dst = exT + ((size_t)b * RPB + l0 + PAD_) * CIN_;
    #pragma unroll
    for (int i = 0; i < 4; ++i) {
        int idx = tid + 256 * i;
        int l  = idx >> 4;                // 16 lanes per row -> 256 B coalesced
        int gc = idx & 15;                // channel granule (8 ch)
        int sw = (l >> 2) & 15;
        bf16x8 vv = *(const bf16x8*)&tileT[l * 136 + ((gc ^ sw) << 3)];
        *(bf16x8*)(dst + (size_t)l * CIN_ + gc * 8) = vv;
    }
}

// Conv GEMM, Round-5 restructure. The R1-R4 variants were all ~serialized:
// LDS-read demand (0.5 KB-reads/MFMA) exceeded the MFMA pipe and waves were
// barrier-phase-locked. Fixes:
//  - A (weights) comes global->VGPR from fragment-ordered ewb (229 KB,
//    L2-resident, reused by all 512 blocks). LDS traffic is B-only:
//    8 reads / 32 MFMAs = 0.25 KB-reads/MFMA -> LDS demand (21.5k cyc/CU)
//    now BELOW MFMA demand (34.8k cyc/CU).
//  - X staged ONCE per block (all 128 ch, 67.6 KB, granule-XOR swizzle
//    g^=(p&7) applied identically on stage-source and read -> <=2-way banks).
//    ONE barrier per block; the 28 tap-chunk compute iterations are
//    barrier-free.
//  - 256-thr blocks (4 waves, wave tile 64o x 128w), 2 blocks/CU genuinely
//    de-phased (no common barrier cadence) -> TLP overlap of stage/compute/
//    epilogue across blocks.
//  - one-deep global A prefetch (named sets afA/afB, static indices).
__global__ __launch_bounds__(256, 2) void tropconv_kernel(
        const __hip_bfloat16* __restrict__ exT,
        const __hip_bfloat16* __restrict__ ewb,
        const float* __restrict__ bias,
        float* __restrict__ out) {
    __shared__ __align__(16) __hip_bfloat16 sX[SX_ELEMS];   // 67584 B

    const int tid  = threadIdx.x;
    const int lane = tid & 63;
    const int wave = tid >> 6;
    const int wm   = wave >> 1;            // 0..1: o half (64 each)
    const int wn   = wave & 1;             // 0..1: w half (128 each)
    const int l15  = lane & 15;
    const int q    = lane >> 4;

    const int b  = blockIdx.y;
    const int w0 = blockIdx.x * NW_;
    const __hip_bfloat16* exb = exT + ((size_t)b * RPB + w0) * CIN_;

    // ---- stage X once: 264 rows x 16 granules = 4224 granules.
    // LDS slot j of row p holds channel-granule j^(p&7) (read applies same XOR).
    #pragma unroll
    for (int s = 0; s < 16; ++s) {
        int gx = tid + 256 * s;
        int p = gx >> 4, j = gx & 15;
        gl2lds16(exb + (p << 7) + ((j ^ (p & 7)) << 3), &sX[gx * 8]);
    }
    if (tid < 128) {                       // waves 0,1 fully active: no intra-wave div
        int gx = tid + 4096;
        int p = gx >> 4, j = gx & 15;
        gl2lds16(exb + (p << 7) + ((j ^ (p & 7)) << 3), &sX[gx * 8]);
    }

    f32x4 acc[4][8];
    #pragma unroll
    for (int i = 0; i < 4; ++i)
        #pragma unroll
        for (int j = 0; j < 8; ++j)
            acc[i][j] = (f32x4){0.f, 0.f, 0.f, 0.f};

    __syncthreads();                       // the block's ONE barrier

    // A-frag (t,cc,mi): 1KB coalesced global load, lane li holds
    // W[og*16+(li&15)][cc*32+(li>>4)*8..+8], og = wm*4+mi.
#define ALOAD(AF, T, CC)                                                     \
    do {                                                                     \
        _Pragma("unroll")                                                    \
        for (int mi = 0; mi < 4; ++mi)                                       \
            AF[mi] = *(const bf16x8*)&ewb[(((((T) * 8 + wm * 4 + mi) * 4     \
                                             + (CC)) << 6) + lane) * 8];     \
    } while (0)

    // B-reads + 32 MFMAs for one (tap, chunk); b128 per lane, <=2-way banks.
#define BDOT(AF, T, CC)                                                      \
    do {                                                                     \
        bf16x8 bx[8];                                                        \
        _Pragma("unroll")                                                    \
        for (int ni = 0; ni < 8; ++ni) {                                     \
            int p = wn * 128 + ni * 16 + l15 + (T);                          \
            int g = ((CC) * 4 + q) ^ (p & 7);                                \
            bx[ni] = *(const bf16x8*)&sX[(p << 7) + (g << 3)];               \
        }                                                                    \
        __builtin_amdgcn_s_setprio(1);                                       \
        _Pragma("unroll")                                                    \
        for (int mi = 0; mi < 4; ++mi)                                       \
            _Pragma("unroll")                                                \
            for (int ni = 0; ni < 8; ++ni)                                   \
                acc[mi][ni] = __builtin_amdgcn_mfma_f32_16x16x32_bf16(       \
                    AF[mi], bx[ni], acc[mi][ni], 0, 0, 0);                   \
        __builtin_amdgcn_s_setprio(0);                                       \
    } while (0)

    {
        bf16x8 afA[4], afB[4];
        ALOAD(afA, 0, 0);
        ALOAD(afB, 1, 0);  BDOT(afA, 0, 0);
        ALOAD(afA, 2, 0);  BDOT(afB, 1, 0);
        ALOAD(afB, 3, 0);  BDOT(afA, 2, 0);
        ALOAD(afA, 4, 0);  BDOT(afB, 3, 0);
        ALOAD(afB, 5, 0);  BDOT(afA, 4, 0);
        ALOAD(afA, 6, 0);  BDOT(afB, 5, 0);
        ALOAD(afB, 0, 1);  BDOT(afA, 6, 0);
        ALOAD(afA, 1, 1);  BDOT(afB, 0, 1);
        ALOAD(afB, 2, 1);  BDOT(afA, 1, 1);
        ALOAD(afA, 3, 1);  BDOT(afB, 2, 1);
        ALOAD(afB, 4, 1);  BDOT(afA, 3, 1);
        ALOAD(afA, 5, 1);  BDOT(afB, 4, 1);
        ALOAD(afB, 6, 1);  BDOT(afA, 5, 1);
        ALOAD(afA, 0, 2);  BDOT(afB, 6, 1);
        ALOAD(afB, 1, 2);  BDOT(afA, 0, 2);
        ALOAD(afA, 2, 2);  BDOT(afB, 1, 2);
        ALOAD(afB, 3, 2);  BDOT(afA, 2, 2);
        ALOAD(afA, 4, 2);  BDOT(afB, 3, 2);
        ALOAD(afB, 5, 2);  BDOT(afA, 4, 2);
        ALOAD(afA, 6, 2);  BDOT(afB, 5, 2);
        ALOAD(afB, 0, 3);  BDOT(afA, 6, 2);
        ALOAD(afA, 1, 3);  BDOT(afB, 0, 3);
        ALOAD(afB, 2, 3);  BDOT(afA, 1, 3);
        ALOAD(afA, 3, 3);  BDOT(afB, 2, 3);
        ALOAD(afB, 4, 3);  BDOT(afA, 3, 3);
        ALOAD(afA, 5, 3);  BDOT(afB, 4, 3);
        ALOAD(afB, 6, 3);  BDOT(afA, 5, 3);
                           BDOT(afB, 6, 3);
    }
#undef ALOAD
#undef BDOT

    // epilogue: y = log(s) + bias[o]; C/D: col=lane&15 (w), row=q*4+reg (cout)
    float* outb = out + (size_t)b * COUT_ * L_;
    #pragma unroll
    for (int mi = 0; mi < 4; ++mi) {
        #pragma unroll
        for (int r = 0; r < 4; ++r) {
            int o = wm * 64 + mi * 16 + q * 4 + r;
            float bv = bias[o];
            #pragma unroll
            for (int ni = 0; ni < 8; ++ni) {
                int w = w0 + wn * 128 + ni * 16 + l15;
                outb[(size_t)o * L_ + w] = __logf(acc[mi][ni][r]) + bv;
            }
        }
    }
}

extern "C" void kernel_launch(void* const* d_in, const int* in_sizes, int n_in,
                              void* d_out, int out_size, void* d_ws, size_t ws_size,
                              hipStream_t stream) {
    const float* x    = (const float*)d_in[0];   // (32,128,4096) f32
    const float* wgt  = (const float*)d_in[1];   // (128,128,7)   f32
    const float* bias = (const float*)d_in[2];   // (128,)        f32
    float* out = (float*)d_out;                  // (32,128,4096) f32

    // workspace: exT (32 x 4104 x 128 bf16 = 33,619,968 B), then ewb (229 KB)
    __hip_bfloat16* exT = (__hip_bfloat16*)d_ws;
    __hip_bfloat16* ewb = (__hip_bfloat16*)((char*)d_ws + (size_t)B_N * RPB * CIN_ * 2);

    exp_x_kernel<<<dim3(64 + 18, B_N), 256, 0, stream>>>(x, exT, wgt, ewb);
    tropconv_kernel<<<dim3(L_ / NW_, B_N), 256, 0, stream>>>(exT, ewb, bias, out);
}